// Round 8
// baseline (294.442 us; speedup 1.0000x reference)
//
#include <hip/hip_runtime.h>
#include <math.h>

// Problem constants
#define NB   16
#define NC   64
#define HWs  4096
#define NPS  1024
#define LOG2E 1.44269504088896341f

// ws layout in ushort (bf16 bit patterns)
static constexpr size_t PHI_OFF = (size_t)NB * HWs * 8;            // theta: [b][4096][8]
static constexpr size_t GT_OFF  = PHI_OFF + (size_t)NB * NPS * 8;  // phi:   [b][1024][8]
// gT: [b][32][1024]; total 1,179,648 ushorts = 2.25 MB

typedef short s16x8 __attribute__((ext_vector_type(8)));
typedef float f32x4 __attribute__((ext_vector_type(4)));

#define LD8G(p) (*(const s16x8*)(p))
#define SB()    __builtin_amdgcn_sched_barrier(0)

__device__ inline unsigned short f2bf(float f) {
    unsigned int u = __float_as_uint(f);
    u += 0x7fffu + ((u >> 16) & 1u);          // RNE
    return (unsigned short)(u >> 16);
}
__device__ inline unsigned int pk2(float a, float b) {
    unsigned int ua = __float_as_uint(a); ua += 0x7fffu + ((ua >> 16) & 1u);
    unsigned int ub = __float_as_uint(b); ub += 0x7fffu + ((ub >> 16) & 1u);
    return (ua >> 16) | (ub & 0xffff0000u);
}

// ---------------------------------------------------------------------------
// Kernel 1 (v4 + waves_per_eu pin): unchanged this round (ablation focuses
// on k_attn; whatever mechanism is found likely transfers).
// ---------------------------------------------------------------------------
__global__ __launch_bounds__(256) __attribute__((amdgpu_waves_per_eu(4, 4)))
void k_proj(
    const float* __restrict__ x, const float* __restrict__ Wt,
    const float* __restrict__ Wp, const float* __restrict__ Wg,
    unsigned short* __restrict__ ws)
{
    __shared__ float xs[64 * 128];            // 32 KB

    unsigned short* theta = ws;
    unsigned short* phi   = ws + PHI_OFF;
    unsigned short* gT    = ws + GT_OFF;

    const int tid  = threadIdx.x;
    const int blk  = blockIdx.x;
    const int b    = blk >> 6;
    const int rp   = (blk >> 1) & 31;         // image rows {2rp, 2rp+1}
    const int half = blk & 1;                 // block-uniform -> SGPR

    const float* xsrc = x + (size_t)b * NC * HWs + rp * 128;
#pragma unroll
    for (int i = 0; i < 8; ++i) {
        const int idx = i * 256 + tid;        // 0..2047 float4 slots
        const int ci  = idx >> 5;
        const int f4  = idx & 31;
        float4 v = *(const float4*)(xsrc + (size_t)ci * HWs + f4 * 4);
        *(float4*)(xs + ci * 128 + f4 * 4) = v;
    }
    __syncthreads();

    const int h   = tid & 127;
    const int sub = __builtin_amdgcn_readfirstlane(tid >> 7);
    const int row = h & 1;
    const int col = h >> 1;
    const int px  = row * 64 + col;

    float a4[4], ag8[8];
#pragma unroll
    for (int j = 0; j < 4; ++j) a4[j] = 0.f;
#pragma unroll
    for (int j = 0; j < 8; ++j) ag8[j] = 0.f;

    const float* W8 = (half ? Wp : Wt) + sub * 4 * NC;   // scalar base
    const float* WG = Wg + (half * 16 + sub * 8) * NC;   // scalar base

#pragma unroll 4
    for (int ci = 0; ci < NC; ++ci) {
        const float xv = xs[ci * 128 + px];   // 2-way bank alias: free
#pragma unroll
        for (int j = 0; j < 4; ++j) a4[j] += W8[j * NC + ci] * xv;    // s_load
#pragma unroll
        for (int j = 0; j < 8; ++j) ag8[j] += WG[j * NC + ci] * xv;   // s_load
    }

    if (half == 0) {
        const int q = (2 * rp + row) * 64 + col;
        uint2 pkd;
        pkd.x = pk2(a4[0] * LOG2E, a4[1] * LOG2E);
        pkd.y = pk2(a4[2] * LOG2E, a4[3] * LOG2E);
        *(uint2*)(theta + ((size_t)b * HWs + q) * 8 + sub * 4) = pkd;
    } else {
#pragma unroll
        for (int j = 0; j < 4; ++j) {
            float v = a4[j];
            v = fmaxf(v, __shfl_xor(v, 1));
            v = fmaxf(v, __shfl_xor(v, 2));
            a4[j] = v;
        }
    }

#pragma unroll
    for (int j = 0; j < 8; ++j) {
        float v = ag8[j];
        v = fmaxf(v, __shfl_xor(v, 1));
        v = fmaxf(v, __shfl_xor(v, 2));
        ag8[j] = v;
    }

    if ((h & 3) == 0) {
        const int ps = rp * 32 + (h >> 2);
        if (half == 1) {
            uint2 pkd;
            pkd.x = pk2(a4[0], a4[1]);
            pkd.y = pk2(a4[2], a4[3]);
            *(uint2*)(phi + ((size_t)b * NPS + ps) * 8 + sub * 4) = pkd;
        }
#pragma unroll
        for (int j = 0; j < 8; ++j) {
            const int c = half * 16 + sub * 8 + j;
            gT[((size_t)b * 32 + c) * NPS + ps] = f2bf(ag8[j]);
        }
    }
}

// ---------------------------------------------------------------------------
// Kernel 2 (v10): ABLATION via template<int V>. Round-12 rationale: five
// structurally different codegens (collapsed, SB-pinned, asm+vmcnt) all land
// at 47-51 us with identical counters; stall arithmetic (~4500-7000 cy/wave/
// tile vs <=900 cy worst-case memory latency) says the mental model is wrong
// at 10x. Ablate before optimizing (guide common-mistake #8).
// Variants (loads = identical asm in ALL variants; phases cut if constexpr;
// DCE-safe: kept phases feed l4 -> 1/l -> otile stores; V2's S is
// t-dependent to defeat LICM):
//   V5 loads-only | V2 no-QK | V3 no-exp | V1 no-PV/no-LDS-P | V0 full
// Launch order: proj, V5, V2, V3, V1, V0(real; overwrites all of out).
// Read-out rule: V5~V0 -> skeleton/loads wall; V1~V0 (V5 fast) -> QK/exp
// wall; V1 fast -> PV/LDS-P wall; all fast -> phase coupling.
// ---------------------------------------------------------------------------
template<int V>
__global__ __launch_bounds__(256) __attribute__((amdgpu_waves_per_eu(4, 4)))
void k_attn_t(
    const float* __restrict__ x, const float* __restrict__ Wo,
    const float* __restrict__ gamma_p, const unsigned short* __restrict__ ws,
    float* __restrict__ out)
{
    constexpr bool DO_CMP  = (V != 5);
    constexpr bool DO_QK   = (V != 2) && DO_CMP;
    constexpr bool DO_EXP  = (V != 3) && DO_CMP;
    constexpr bool DO_PV   = (V != 1) && DO_CMP;   // PV MFMAs + P LDS bounce

    __shared__ __align__(16) unsigned char smem[18432];

    const int tid  = threadIdx.x;
    const int wave = __builtin_amdgcn_readfirstlane(tid >> 6);
    const int lane = tid & 63;
    const int quad = lane >> 4, lr = lane & 15;
    const int blk  = blockIdx.x;
    const int b    = blk >> 6;
    const int q0   = (blk & 63) * 64;

    const unsigned short* th = ws + (size_t)b * HWs * 8;
    const unsigned short* ph = ws + PHI_OFF + (size_t)b * NPS * 8;
    const unsigned short* gp = ws + GT_OFF + (size_t)b * 32 * NPS;
    unsigned short* Pw = (unsigned short*)smem + wave * 2304;   // 2 bufs x [16 q][72 s]

    const s16x8 zf = {0, 0, 0, 0, 0, 0, 0, 0};
    const f32x4 zc = {0.f, 0.f, 0.f, 0.f};

    const s16x8 thA = (quad == 0) ? LD8G(th + (size_t)(q0 + wave * 16 + lr) * 8) : zf;

    f32x4 O[2];
    f32x4 l4;
#pragma unroll
    for (int r = 0; r < 4; ++r) { O[0][r] = 0.f; O[1][r] = 0.f; l4[r] = 0.f; }

    // loop-invariant per-lane byte voffsets
    const int voff_ph0 = (0 * 16 + lr) * 16;
    const int voff_ph1 = (1 * 16 + lr) * 16;
    const int voff_ph2 = (2 * 16 + lr) * 16;
    const int voff_ph3 = (3 * 16 + lr) * 16;
    const int voff_g00 = ((0 * 16 + lr) * NPS + 0 * 32 + quad * 8) * 2;
    const int voff_g01 = ((1 * 16 + lr) * NPS + 0 * 32 + quad * 8) * 2;
    const int voff_g10 = ((0 * 16 + lr) * NPS + 1 * 32 + quad * 8) * 2;
    const int voff_g11 = ((1 * 16 + lr) * NPS + 1 * 32 + quad * 8) * 2;

    s16x8 phB_e[4], phB_o[4];
    s16x8 Gf_e[2][2], Gf_o[2][2];

#define GL4(dst, off, base)                                                   \
    asm volatile("global_load_dwordx4 %0, %1, %2"                             \
                 : "=v"(dst) : "v"(off), "s"(base) : "memory")

#define LOADPH_A(dst, baseT)                                                  \
    GL4(dst[0], voff_ph0, baseT); GL4(dst[1], voff_ph1, baseT);               \
    GL4(dst[2], voff_ph2, baseT); GL4(dst[3], voff_ph3, baseT);

#define LOADG_A(dst, baseT)                                                   \
    GL4(dst[0][0], voff_g00, baseT); GL4(dst[0][1], voff_g01, baseT);         \
    GL4(dst[1][0], voff_g10, baseT); GL4(dst[1][1], voff_g11, baseT);

#define WAITVM(n) asm volatile("s_waitcnt vmcnt(" #n ")" ::: "memory")

#define QKV(Sv, phB, tt)                                                      \
    if constexpr (DO_QK) {                                                    \
        _Pragma("unroll")                                                     \
        for (int ss = 0; ss < 4; ++ss)                                        \
            Sv[ss] = __builtin_amdgcn_mfma_f32_16x16x32_bf16(thA, phB[ss], zc, 0, 0, 0); \
    } else {                                                                  \
        _Pragma("unroll")                                                     \
        for (int ss = 0; ss < 4; ++ss)                                        \
            _Pragma("unroll")                                                 \
            for (int r = 0; r < 4; ++r)                                       \
                Sv[ss][r] = 0.0625f * (float)(ss * 4 + r + 1)                 \
                          + 0.001f * (float)(tt);  /* t-dep: defeats LICM */  \
    }

#define EXPST(Sv, wbuf)                                                       \
    _Pragma("unroll")                                                         \
    for (int ss = 0; ss < 4; ++ss)                                            \
        _Pragma("unroll")                                                     \
        for (int r = 0; r < 4; ++r) {                                         \
            float p;                                                          \
            if constexpr (DO_EXP) p = exp2f(Sv[ss][r]);                       \
            else                  p = Sv[ss][r] * 0.0625f;                    \
            l4[r] += p;                                                       \
            if constexpr (DO_PV)                                              \
                Pw[(wbuf) + (quad * 4 + r) * 72 + ss * 16 + lr] =             \
                    (unsigned short)(__float_as_uint(p) >> 16);               \
        }

#define BODY(phCUR, GfPREV, GfCUR, phNXT, curT, rbuf, wbuf)                   \
    {                                                                         \
        const unsigned short* gbT  = gp + (size_t)(curT) * 64;                \
        const unsigned short* phT1 = ph + (size_t)((curT) + 1) * 512;         \
        LOADG_A(GfCUR, gbT);                                                  \
        LOADPH_A(phNXT, phT1);                                                \
        s16x8 Pf0 = zf, Pf1 = zf;                                             \
        if constexpr (DO_PV) {                                                \
            Pf0 = *(const s16x8*)(Pw + (rbuf) + lr * 72 + quad * 8);          \
            Pf1 = *(const s16x8*)(Pw + (rbuf) + lr * 72 + 32 + quad * 8);     \
        }                                                                     \
        WAITVM(8);                                                            \
        SB();                                                                 \
        if constexpr (DO_CMP) {                                               \
            f32x4 S[4];                                                       \
            QKV(S, phCUR, curT);                                              \
            if constexpr (DO_PV) {                                            \
                _Pragma("unroll")                                             \
                for (int cs = 0; cs < 2; ++cs)                                \
                    O[cs] = __builtin_amdgcn_mfma_f32_16x16x32_bf16(Pf0, GfPREV[0][cs], O[cs], 0, 0, 0); \
                _Pragma("unroll")                                             \
                for (int cs = 0; cs < 2; ++cs)                                \
                    O[cs] = __builtin_amdgcn_mfma_f32_16x16x32_bf16(Pf1, GfPREV[1][cs], O[cs], 0, 0, 0); \
            }                                                                 \
            EXPST(S, wbuf);                                                   \
        } else {                                                              \
            l4[0] += 1.0f;                                                    \
        }                                                                     \
    }

    // ---- prologue: issue ph0, G0, ph1 (12 loads); wait ph0 (vmcnt(8)) ----
    LOADPH_A(phB_e, ph);
    LOADG_A(Gf_e, gp);
    {
        const unsigned short* ph1 = ph + 512;
        LOADPH_A(phB_o, ph1);
    }
    WAITVM(8);
    SB();
    if constexpr (DO_CMP) {
        f32x4 S[4];
        QKV(S, phB_e, 0);
        EXPST(S, 0);
    } else { l4[0] += 1.0f; }

    // ---- steady state: pairs (t odd, t+1 even), t = 1..13 ----
    for (int t = 1; t < 15; t += 2) {
        BODY(phB_o, Gf_e, Gf_o, phB_e, t,     0,    1152);
        BODY(phB_e, Gf_o, Gf_e, phB_o, t + 1, 1152, 0);
    }

    // ---- t = 15 (odd; only G15 to issue) ----
    {
        const unsigned short* gb15 = gp + (size_t)15 * 64;
        LOADG_A(Gf_o, gb15);
        s16x8 Pf0 = zf, Pf1 = zf;
        if constexpr (DO_PV) {
            Pf0 = *(const s16x8*)(Pw + 0 + lr * 72 + quad * 8);
            Pf1 = *(const s16x8*)(Pw + 0 + lr * 72 + 32 + quad * 8);
        }
        WAITVM(4);
        SB();
        if constexpr (DO_CMP) {
            f32x4 S[4];
            QKV(S, phB_o, 15);
            if constexpr (DO_PV) {
#pragma unroll
                for (int cs = 0; cs < 2; ++cs)
                    O[cs] = __builtin_amdgcn_mfma_f32_16x16x32_bf16(Pf0, Gf_e[0][cs], O[cs], 0, 0, 0);
#pragma unroll
                for (int cs = 0; cs < 2; ++cs)
                    O[cs] = __builtin_amdgcn_mfma_f32_16x16x32_bf16(Pf1, Gf_e[1][cs], O[cs], 0, 0, 0);
            }
            EXPST(S, 1152);
        } else { l4[0] += 1.0f; }
    }

    // ---- drain ----
    {
        WAITVM(0);
        SB();
        if constexpr (DO_PV) {
            const s16x8 Pf0 = *(const s16x8*)(Pw + 1152 + lr * 72 + quad * 8);
            const s16x8 Pf1 = *(const s16x8*)(Pw + 1152 + lr * 72 + 32 + quad * 8);
#pragma unroll
            for (int cs = 0; cs < 2; ++cs)
                O[cs] = __builtin_amdgcn_mfma_f32_16x16x32_bf16(Pf0, Gf_o[0][cs], O[cs], 0, 0, 0);
#pragma unroll
            for (int cs = 0; cs < 2; ++cs)
                O[cs] = __builtin_amdgcn_mfma_f32_16x16x32_bf16(Pf1, Gf_o[1][cs], O[cs], 0, 0, 0);
        }
    }

    // l reduce
#pragma unroll
    for (int r = 0; r < 4; ++r) {
        float v = l4[r];
        v += __shfl_xor(v, 1);
        v += __shfl_xor(v, 2);
        v += __shfl_xor(v, 4);
        v += __shfl_xor(v, 8);
        l4[r] = 1.f / v;
    }

    __syncthreads();
    float* otile = (float*)smem;              // [32 c][68 q-stride]
#pragma unroll
    for (int cs = 0; cs < 2; ++cs) {
        f32x4 v;
#pragma unroll
        for (int r = 0; r < 4; ++r) v[r] = O[cs][r] * l4[r];
        *(f32x4*)(otile + (cs * 16 + lr) * 68 + wave * 16 + quad * 4) = v;
    }
    __syncthreads();

    // Wo epilogue + residual (identical in all variants)
    const int qq = tid & 63;
    const int quarter = __builtin_amdgcn_readfirstlane(tid >> 6);
    float ov[32];
#pragma unroll
    for (int c = 0; c < 32; ++c) ov[c] = otile[c * 68 + qq];
    const float gam = gamma_p[0];
#pragma unroll
    for (int j = 0; j < 16; ++j) {
        const float* wrow = Wo + (size_t)(quarter * 16 + j) * 32;
        float a = 0.f;
#pragma unroll
        for (int c = 0; c < 32; ++c) a += wrow[c] * ov[c];
        const size_t ad = ((size_t)b * NC + quarter * 16 + j) * HWs + q0 + qq;
        out[ad] = gam * a + x[ad];
    }
}

extern "C" void kernel_launch(void* const* d_in, const int* in_sizes, int n_in,
                              void* d_out, int out_size, void* d_ws, size_t ws_size,
                              hipStream_t stream) {
    const float* x     = (const float*)d_in[0];
    const float* Wt    = (const float*)d_in[1];
    const float* Wp    = (const float*)d_in[2];
    const float* Wg    = (const float*)d_in[3];
    const float* Wo    = (const float*)d_in[4];
    const float* gamma = (const float*)d_in[5];
    float* out = (float*)d_out;
    unsigned short* ws = (unsigned short*)d_ws;

    k_proj<<<1024, 256, 0, stream>>>(x, Wt, Wp, Wg, ws);
    // Ablation dispatches (out garbage, fully overwritten by the final V0)
    k_attn_t<5><<<1024, 256, 0, stream>>>(x, Wo, gamma, ws, out);  // loads only
    k_attn_t<2><<<1024, 256, 0, stream>>>(x, Wo, gamma, ws, out);  // no QK
    k_attn_t<3><<<1024, 256, 0, stream>>>(x, Wo, gamma, ws, out);  // no exp
    k_attn_t<1><<<1024, 256, 0, stream>>>(x, Wo, gamma, ws, out);  // no PV/LDS-P
    // Real kernel (overwrites every element of out)
    k_attn_t<0><<<1024, 256, 0, stream>>>(x, Wo, gamma, ws, out);
}

// Round 9
// 114.219 us; speedup vs baseline: 2.5779x; 2.5779x over previous
//
#include <hip/hip_runtime.h>
#include <math.h>

// Problem constants
#define NB   16
#define NC   64
#define HWs  4096
#define NPS  1024
#define LOG2E 1.44269504088896341f

// ws layout in ushort (bf16 bit patterns)
static constexpr size_t PHI_OFF = (size_t)NB * HWs * 8;            // theta: [b][4096][8]
static constexpr size_t GT_OFF  = PHI_OFF + (size_t)NB * NPS * 8;  // phi:   [b][1024][8]
// gT: [b][32][1024]; total 1,179,648 ushorts = 2.25 MB

typedef short s16x8 __attribute__((ext_vector_type(8)));
typedef float f32x4 __attribute__((ext_vector_type(4)));

#define LD8G(p) (*(const s16x8*)(p))
#define SB()    __builtin_amdgcn_sched_barrier(0)

__device__ inline unsigned short f2bf(float f) {
    unsigned int u = __float_as_uint(f);
    u += 0x7fffu + ((u >> 16) & 1u);          // RNE
    return (unsigned short)(u >> 16);
}
__device__ inline unsigned int pk2(float a, float b) {
    unsigned int ua = __float_as_uint(a); ua += 0x7fffu + ((ua >> 16) & 1u);
    unsigned int ub = __float_as_uint(b); ub += 0x7fffu + ((ub >> 16) & 1u);
    return (ua >> 16) | (ub & 0xffff0000u);
}

// ---------------------------------------------------------------------------
// Kernel 1 (v4): unchanged. True cost ~34 us (round-9 finding: dur_us always
// includes a ~47 us 268-MB workspace-poison memset; k_proj was never 51).
// ---------------------------------------------------------------------------
__global__ __launch_bounds__(256) __attribute__((amdgpu_waves_per_eu(4, 4)))
void k_proj(
    const float* __restrict__ x, const float* __restrict__ Wt,
    const float* __restrict__ Wp, const float* __restrict__ Wg,
    unsigned short* __restrict__ ws)
{
    __shared__ float xs[64 * 128];            // 32 KB

    unsigned short* theta = ws;
    unsigned short* phi   = ws + PHI_OFF;
    unsigned short* gT    = ws + GT_OFF;

    const int tid  = threadIdx.x;
    const int blk  = blockIdx.x;
    const int b    = blk >> 6;
    const int rp   = (blk >> 1) & 31;         // image rows {2rp, 2rp+1}
    const int half = blk & 1;                 // block-uniform -> SGPR

    const float* xsrc = x + (size_t)b * NC * HWs + rp * 128;
#pragma unroll
    for (int i = 0; i < 8; ++i) {
        const int idx = i * 256 + tid;        // 0..2047 float4 slots
        const int ci  = idx >> 5;
        const int f4  = idx & 31;
        float4 v = *(const float4*)(xsrc + (size_t)ci * HWs + f4 * 4);
        *(float4*)(xs + ci * 128 + f4 * 4) = v;
    }
    __syncthreads();

    const int h   = tid & 127;
    const int sub = __builtin_amdgcn_readfirstlane(tid >> 7);
    const int row = h & 1;
    const int col = h >> 1;
    const int px  = row * 64 + col;

    float a4[4], ag8[8];
#pragma unroll
    for (int j = 0; j < 4; ++j) a4[j] = 0.f;
#pragma unroll
    for (int j = 0; j < 8; ++j) ag8[j] = 0.f;

    const float* W8 = (half ? Wp : Wt) + sub * 4 * NC;   // scalar base
    const float* WG = Wg + (half * 16 + sub * 8) * NC;   // scalar base

#pragma unroll 4
    for (int ci = 0; ci < NC; ++ci) {
        const float xv = xs[ci * 128 + px];   // 2-way bank alias: free
#pragma unroll
        for (int j = 0; j < 4; ++j) a4[j] += W8[j * NC + ci] * xv;    // s_load
#pragma unroll
        for (int j = 0; j < 8; ++j) ag8[j] += WG[j * NC + ci] * xv;   // s_load
    }

    if (half == 0) {
        const int q = (2 * rp + row) * 64 + col;
        uint2 pkd;
        pkd.x = pk2(a4[0] * LOG2E, a4[1] * LOG2E);
        pkd.y = pk2(a4[2] * LOG2E, a4[3] * LOG2E);
        *(uint2*)(theta + ((size_t)b * HWs + q) * 8 + sub * 4) = pkd;
    } else {
#pragma unroll
        for (int j = 0; j < 4; ++j) {
            float v = a4[j];
            v = fmaxf(v, __shfl_xor(v, 1));
            v = fmaxf(v, __shfl_xor(v, 2));
            a4[j] = v;
        }
    }

#pragma unroll
    for (int j = 0; j < 8; ++j) {
        float v = ag8[j];
        v = fmaxf(v, __shfl_xor(v, 1));
        v = fmaxf(v, __shfl_xor(v, 2));
        ag8[j] = v;
    }

    if ((h & 3) == 0) {
        const int ps = rp * 32 + (h >> 2);
        if (half == 1) {
            uint2 pkd;
            pkd.x = pk2(a4[0], a4[1]);
            pkd.y = pk2(a4[2], a4[3]);
            *(uint2*)(phi + ((size_t)b * NPS + ps) * 8 + sub * 4) = pkd;
        }
#pragma unroll
        for (int j = 0; j < 8; ++j) {
            const int c = half * 16 + sub * 8 + j;
            gT[((size_t)b * 32 + c) * NPS + ps] = f2bf(ag8[j]);
        }
    }
}

// ---------------------------------------------------------------------------
// Kernel 2 (v11): L2-dedup + tile stagger.
// Round-13 theory (from v10 ablation): all phase ablations ~= full kernel ->
// the wall is the LOADS. They are redundant: Gf/phB voffsets don't depend on
// wave -> 4x intra-block duplication; 64 q-blocks/batch re-read the same
// 80 KB phi/gT in LOCK-STEP tile order -> ~512 MB of L2-line traffic through
// the same hot lines at ~13 TB/s effective = V5's ~40 us floor.
// v11: (1) G-tile (4 KB) staged ONCE per block: each of 256 threads asm-loads
// one 16B chunk -> ds_write XOR-swizzled into stage[2][4KB]; PV reads frags
// via swizzled ds_read_b128 (kills stride-128B bank conflict). One
// __syncthreads per tile = the cross-wave hand-off. (2) Stagger tile order
// st=(t+blk&15)&15 — legal: non-online softmax, tile order is permutation-
// invariant for l4 and O. 16x fewer concurrent readers per L2 line.
// vmcnt ledger: 5 loads/body (4 phi + 1 G-chunk); vmcnt(4) before ds_write
// (retires G chunk), vmcnt(5) before QK (retires phi), body-15 waits 0.
// LDS: P 18432 + stage 8192 = 26624 B; otile epilogue reuses [0, 8704).
// Checks: FETCH ~14.5 MB (spill tripwire), LDS_Block_Size 26624.
// ---------------------------------------------------------------------------
__global__ __launch_bounds__(256) __attribute__((amdgpu_waves_per_eu(4, 4)))
void k_attn(
    const float* __restrict__ x, const float* __restrict__ Wo,
    const float* __restrict__ gamma_p, const unsigned short* __restrict__ ws,
    float* __restrict__ out)
{
    __shared__ __align__(16) unsigned char smem[26624];

    const int tid  = threadIdx.x;
    const int wave = __builtin_amdgcn_readfirstlane(tid >> 6);
    const int lane = tid & 63;
    const int quad = lane >> 4, lr = lane & 15;
    const int blk  = blockIdx.x;
    const int b    = blk >> 6;
    const int q0   = (blk & 63) * 64;
    const int stoff = blk & 15;               // tile stagger (block-uniform)

    const unsigned short* th = ws + (size_t)b * HWs * 8;
    const unsigned short* ph = ws + PHI_OFF + (size_t)b * NPS * 8;
    const unsigned short* gp = ws + GT_OFF + (size_t)b * 32 * NPS;
    unsigned short* Pw  = (unsigned short*)smem + wave * 2304;     // 2 bufs x [16 q][72 s]
    unsigned short* stg = (unsigned short*)(smem + 18432);         // 2 bufs x [32 ch][64 s]

    // G staging map: thread -> one 16B chunk (ch = tid>>3, part = tid&7),
    // XOR-swizzled column so frag reads spread across banks.
    const int sch   = tid >> 3;
    const int spart = tid & 7;
    const int swz   = spart ^ (sch & 7);
    const int voff_gc = sch * (NPS * 2) + spart * 16;   // byte voffset into gT slab

    const s16x8 zf = {0, 0, 0, 0, 0, 0, 0, 0};
    const f32x4 zc = {0.f, 0.f, 0.f, 0.f};

    // theta A-fragment: A[m=q=lr][k=quad*8+j], real k<8 in quad 0
    const s16x8 thA = (quad == 0) ? LD8G(th + (size_t)(q0 + wave * 16 + lr) * 8) : zf;

    f32x4 O[2];
    f32x4 l4;
#pragma unroll
    for (int r = 0; r < 4; ++r) { O[0][r] = 0.f; O[1][r] = 0.f; l4[r] = 0.f; }

    // per-lane phi byte voffsets (loop-invariant)
    const int voff_ph0 = (0 * 16 + lr) * 16;
    const int voff_ph1 = (1 * 16 + lr) * 16;
    const int voff_ph2 = (2 * 16 + lr) * 16;
    const int voff_ph3 = (3 * 16 + lr) * 16;

    s16x8 phB_e[4], phB_o[4];
    s16x8 greg_e, greg_o;

#define GL4(dst, off, base)                                                   \
    asm volatile("global_load_dwordx4 %0, %1, %2"                             \
                 : "=v"(dst) : "v"(off), "s"(base) : "memory")

#define LOADPH_A(dst, baseT)                                                  \
    GL4(dst[0], voff_ph0, baseT); GL4(dst[1], voff_ph1, baseT);               \
    GL4(dst[2], voff_ph2, baseT); GL4(dst[3], voff_ph3, baseT);

#define WAITVM(n) asm volatile("s_waitcnt vmcnt(" #n ")" ::: "memory")

#define QK(Sv, phB)                                                           \
    _Pragma("unroll")                                                         \
    for (int ss = 0; ss < 4; ++ss)                                            \
        Sv[ss] = __builtin_amdgcn_mfma_f32_16x16x32_bf16(thA, phB[ss], zc, 0, 0, 0);

#define EXPST(Sv, wbuf)                                                       \
    _Pragma("unroll")                                                         \
    for (int ss = 0; ss < 4; ++ss)                                            \
        _Pragma("unroll")                                                     \
        for (int r = 0; r < 4; ++r) {                                         \
            const float p = exp2f(Sv[ss][r]);                                 \
            l4[r] += p;                                                       \
            Pw[(wbuf) + (quad * 4 + r) * 72 + ss * 16 + lr] =                 \
                (unsigned short)(__float_as_uint(p) >> 16);                   \
        }

// Body t (t>=1): QK on tile st(t) (phi prefetched in regs), PV on st(t-1)
// (P from Pw[(t-1)&1], G frags from stage[(t-1)&1]); stage G(st(t)) (reg
// loaded last body) into stage[t&1]; issue G(st(t+1)) + phi(st(t+1)).
// Barrier at top: separates prev body's stage reads from this body's write
// to the same buffer, and prev body's writes from this body's reads.
#define BODY(phCUR, phNXT, gCUR, gNXT, curT, LAST)                            \
    {                                                                         \
        WAITVM(4);   /* retire G chunk of st(curT) (oldest of 5) */           \
        __syncthreads();                                                      \
        *(s16x8*)(stg + ((curT) & 1) * 2048 + sch * 64 + swz * 8) = gCUR;     \
        if (!(LAST)) {                                                        \
            const int stn = ((curT) + 1 + stoff) & 15;                        \
            GL4(gNXT, voff_gc, gp + (size_t)stn * 64);                        \
            LOADPH_A(phNXT, ph + (size_t)stn * 512);                          \
        }                                                                     \
        const int pb = ((curT) - 1) & 1;                                      \
        const s16x8 Pf0 = *(const s16x8*)(Pw + pb * 1152 + lr * 72 + quad * 8);      \
        const s16x8 Pf1 = *(const s16x8*)(Pw + pb * 1152 + lr * 72 + 32 + quad * 8); \
        s16x8 Gf[2][2];                                                       \
        _Pragma("unroll")                                                     \
        for (int kc = 0; kc < 2; ++kc)                                        \
            _Pragma("unroll")                                                 \
            for (int cs = 0; cs < 2; ++cs)                                    \
                Gf[kc][cs] = *(const s16x8*)(stg + pb * 2048 +                \
                    (cs * 16 + lr) * 64 + ((kc * 4 + quad) ^ (lr & 7)) * 8);  \
        if (LAST) { WAITVM(0); } else { WAITVM(5); }  /* phi(st(curT)) */     \
        SB();                                                                 \
        f32x4 S[4];                                                           \
        QK(S, phCUR);                                                         \
        _Pragma("unroll")                                                     \
        for (int cs = 0; cs < 2; ++cs)                                        \
            O[cs] = __builtin_amdgcn_mfma_f32_16x16x32_bf16(Pf0, Gf[0][cs], O[cs], 0, 0, 0); \
        _Pragma("unroll")                                                     \
        for (int cs = 0; cs < 2; ++cs)                                        \
            O[cs] = __builtin_amdgcn_mfma_f32_16x16x32_bf16(Pf1, Gf[1][cs], O[cs], 0, 0, 0); \
        EXPST(S, ((curT) & 1) * 1152);                                        \
    }

    // ---- prologue: tile st(0) ----
    {
        const int st0 = stoff;
        const int st1 = (stoff + 1) & 15;
        GL4(greg_e, voff_gc, gp + (size_t)st0 * 64);
        LOADPH_A(phB_e, ph + (size_t)st0 * 512);
        WAITVM(4);                              // retire G(st0)
        *(s16x8*)(stg + 0 * 2048 + sch * 64 + swz * 8) = greg_e;
        GL4(greg_o, voff_gc, gp + (size_t)st1 * 64);
        LOADPH_A(phB_o, ph + (size_t)st1 * 512);
        WAITVM(5);                              // retire phi(st0)
        SB();
        f32x4 S[4];
        QK(S, phB_e);
        EXPST(S, 0);
    }

    // ---- steady state: t = 1..14 in ping-pong pairs ----
    for (int t = 1; t < 15; t += 2) {
        BODY(phB_o, phB_e, greg_o, greg_e, t,     0);
        BODY(phB_e, phB_o, greg_e, greg_o, t + 1, 0);
    }
    // ---- t = 15 (no next prefetch) ----
    BODY(phB_o, phB_e, greg_o, greg_e, 15, 1);

    // ---- drain: PV for tile st(15) (P in buf1, G in stage[1]) ----
    {
        __syncthreads();                        // stage[1] written by all
        const s16x8 Pf0 = *(const s16x8*)(Pw + 1152 + lr * 72 + quad * 8);
        const s16x8 Pf1 = *(const s16x8*)(Pw + 1152 + lr * 72 + 32 + quad * 8);
        s16x8 Gf[2][2];
#pragma unroll
        for (int kc = 0; kc < 2; ++kc)
#pragma unroll
            for (int cs = 0; cs < 2; ++cs)
                Gf[kc][cs] = *(const s16x8*)(stg + 2048 +
                    (cs * 16 + lr) * 64 + ((kc * 4 + quad) ^ (lr & 7)) * 8);
#pragma unroll
        for (int cs = 0; cs < 2; ++cs)
            O[cs] = __builtin_amdgcn_mfma_f32_16x16x32_bf16(Pf0, Gf[0][cs], O[cs], 0, 0, 0);
#pragma unroll
        for (int cs = 0; cs < 2; ++cs)
            O[cs] = __builtin_amdgcn_mfma_f32_16x16x32_bf16(Pf1, Gf[1][cs], O[cs], 0, 0, 0);
    }

    // l: butterfly-sum over the 16-lane s-groups
#pragma unroll
    for (int r = 0; r < 4; ++r) {
        float v = l4[r];
        v += __shfl_xor(v, 1);
        v += __shfl_xor(v, 2);
        v += __shfl_xor(v, 4);
        v += __shfl_xor(v, 8);
        l4[r] = 1.f / v;
    }

    __syncthreads();                          // all waves done with Pw/stage
    float* otile = (float*)smem;              // [32 c][68 q-stride]
#pragma unroll
    for (int cs = 0; cs < 2; ++cs) {
        f32x4 v;
#pragma unroll
        for (int r = 0; r < 4; ++r) v[r] = O[cs][r] * l4[r];
        *(f32x4*)(otile + (cs * 16 + lr) * 68 + wave * 16 + quad * 4) = v;
    }
    __syncthreads();

    // Wo epilogue + residual: thread = (q = tid&63, oc quarter = tid>>6)
    const int qq = tid & 63;
    const int quarter = __builtin_amdgcn_readfirstlane(tid >> 6);
    float ov[32];
#pragma unroll
    for (int c = 0; c < 32; ++c) ov[c] = otile[c * 68 + qq];
    const float gam = gamma_p[0];
#pragma unroll
    for (int j = 0; j < 16; ++j) {
        const float* wrow = Wo + (size_t)(quarter * 16 + j) * 32;  // contiguous
        float a = 0.f;
#pragma unroll
        for (int c = 0; c < 32; ++c) a += wrow[c] * ov[c];         // s_load
        const size_t ad = ((size_t)b * NC + quarter * 16 + j) * HWs + q0 + qq;
        out[ad] = gam * a + x[ad];
    }
}

extern "C" void kernel_launch(void* const* d_in, const int* in_sizes, int n_in,
                              void* d_out, int out_size, void* d_ws, size_t ws_size,
                              hipStream_t stream) {
    const float* x     = (const float*)d_in[0];
    const float* Wt    = (const float*)d_in[1];
    const float* Wp    = (const float*)d_in[2];
    const float* Wg    = (const float*)d_in[3];
    const float* Wo    = (const float*)d_in[4];
    const float* gamma = (const float*)d_in[5];
    float* out = (float*)d_out;
    unsigned short* ws = (unsigned short*)d_ws;

    k_proj<<<1024, 256, 0, stream>>>(x, Wt, Wp, Wg, ws);
    k_attn<<<1024, 256, 0, stream>>>(x, Wo, gamma, ws, out);
}

// Round 10
// 111.974 us; speedup vs baseline: 2.6296x; 1.0200x over previous
//
#include <hip/hip_runtime.h>
#include <math.h>

// Problem constants
#define NB   16
#define NC   64
#define HWs  4096
#define NPS  1024
#define LOG2E 1.44269504088896341f

// ws layout in ushort (bf16 bit patterns)
static constexpr size_t PHI_OFF = (size_t)NB * HWs * 8;            // theta: [b][4096][8]
static constexpr size_t GT_OFF  = PHI_OFF + (size_t)NB * NPS * 8;  // phi:   [b][1024][8]
// gT: [b][32][1024]; total 1,179,648 ushorts = 2.25 MB

typedef short s16x8 __attribute__((ext_vector_type(8)));
typedef float f32x4 __attribute__((ext_vector_type(4)));

#define LD8G(p) (*(const s16x8*)(p))
#define SB()    __builtin_amdgcn_sched_barrier(0)

__device__ inline unsigned short f2bf(float f) {
    unsigned int u = __float_as_uint(f);
    u += 0x7fffu + ((u >> 16) & 1u);          // RNE
    return (unsigned short)(u >> 16);
}
__device__ inline unsigned int pk2(float a, float b) {
    unsigned int ua = __float_as_uint(a); ua += 0x7fffu + ((ua >> 16) & 1u);
    unsigned int ub = __float_as_uint(b); ub += 0x7fffu + ((ub >> 16) & 1u);
    return (ua >> 16) | (ub & 0xffff0000u);
}

// ---------------------------------------------------------------------------
// Kernel 1 (v5): quarter-split blocks for 8 waves/SIMD.
// Round-14 analysis: k_proj ~30 us vs ~4 us issue floor (85% stalled on
// ds_read->FMA chains + s_load waits at only 4 waves/SIMD; 32KB LDS caps
// residency). v5: split each block's column range in two -> 2048 blocks
// (b x rp x half x csub), LDS 16 KB (64ci x 64px fp32), 256 thr = 64 px x
// 4 groups (2 theta/phi ch + 4 g ch; 6 MACs/ci). 8 blocks/CU x 16KB = 128KB,
// 32 waves/CU = 8 waves/SIMD (VGPR << 64, pinned waves_per_eu(8,8)).
// x traffic unchanged (32 MB total). Pool pairs in-wave: row=xor32, col=xor1.
// Coverage: theta ch 0-7 (half0, grp*2), phi ch 0-7 (half1), g ch 0-31
// (half*16+grp*4); ps = rp*32 + csub*16 + c/2 — each output written once.
// ---------------------------------------------------------------------------
__global__ __launch_bounds__(256) __attribute__((amdgpu_waves_per_eu(8, 8)))
void k_proj(
    const float* __restrict__ x, const float* __restrict__ Wt,
    const float* __restrict__ Wp, const float* __restrict__ Wg,
    unsigned short* __restrict__ ws)
{
    __shared__ float xs[64 * 64];             // 16 KB

    unsigned short* theta = ws;
    unsigned short* phi   = ws + PHI_OFF;
    unsigned short* gT    = ws + GT_OFF;

    const int tid  = threadIdx.x;
    const int blk  = blockIdx.x;
    const int b    = blk >> 7;
    const int rp   = (blk >> 2) & 31;         // image rows {2rp, 2rp+1}
    const int half = (blk >> 1) & 1;          // block-uniform -> SGPR
    const int csub = blk & 1;                 // column half (32 cols)
    const int col0 = csub * 32;

    // ---- stage x[b][ci][rows 2rp,2rp+1][cols col0..col0+32) -> xs[ci][64] ----
    const float* xsrc = x + (size_t)b * NC * HWs + rp * 128;
#pragma unroll
    for (int i = 0; i < 4; ++i) {
        const int idx  = i * 256 + tid;       // 0..1023 float4 slots
        const int ci   = idx >> 4;
        const int slot = idx & 15;            // r = slot>>3, c4 = slot&7
        const int r    = slot >> 3;
        const int c4   = slot & 7;
        float4 v = *(const float4*)(xsrc + (size_t)ci * HWs + r * 64 + col0 + c4 * 4);
        *(float4*)(xs + ci * 64 + r * 32 + c4 * 4) = v;
    }
    __syncthreads();

    const int pxl = tid & 63;                 // r = pxl>>5, c = pxl&31
    const int r   = pxl >> 5;
    const int c   = pxl & 31;
    const int grp = __builtin_amdgcn_readfirstlane(tid >> 6);   // 0..3, SGPR

    float a2[2], ag4[4];
#pragma unroll
    for (int j = 0; j < 2; ++j) a2[j] = 0.f;
#pragma unroll
    for (int j = 0; j < 4; ++j) ag4[j] = 0.f;

    const float* W8 = (half ? Wp : Wt) + grp * 2 * NC;           // scalar base
    const float* WG = Wg + (half * 16 + grp * 4) * NC;           // scalar base

#pragma unroll 8
    for (int ci = 0; ci < NC; ++ci) {
        const float xv = xs[ci * 64 + pxl];   // 2-way bank alias: free
#pragma unroll
        for (int j = 0; j < 2; ++j) a2[j] += W8[j * NC + ci] * xv;    // s_load
#pragma unroll
        for (int j = 0; j < 4; ++j) ag4[j] += WG[j * NC + ci] * xv;   // s_load
    }

    if (half == 0) {
        // theta: unpooled, scaled by log2e; channels grp*2 .. grp*2+2
        const int q = (2 * rp + r) * 64 + col0 + c;
        *(unsigned int*)(theta + ((size_t)b * HWs + q) * 8 + grp * 2) =
            pk2(a2[0] * LOG2E, a2[1] * LOG2E);
    } else {
        // phi pooling: row pair (xor 32), col pair (xor 1)
#pragma unroll
        for (int j = 0; j < 2; ++j) {
            float v = a2[j];
            v = fmaxf(v, __shfl_xor(v, 32));
            v = fmaxf(v, __shfl_xor(v, 1));
            a2[j] = v;
        }
    }

    // g pooling (both halves)
#pragma unroll
    for (int j = 0; j < 4; ++j) {
        float v = ag4[j];
        v = fmaxf(v, __shfl_xor(v, 32));
        v = fmaxf(v, __shfl_xor(v, 1));
        ag4[j] = v;
    }

    if (r == 0 && (c & 1) == 0) {
        const int ps = rp * 32 + csub * 16 + (c >> 1);
        if (half == 1) {
            *(unsigned int*)(phi + ((size_t)b * NPS + ps) * 8 + grp * 2) =
                pk2(a2[0], a2[1]);
        }
#pragma unroll
        for (int j = 0; j < 4; ++j) {
            const int ch = half * 16 + grp * 4 + j;
            gT[((size_t)b * 32 + ch) * NPS + ps] = f2bf(ag4[j]);
        }
    }
}

// ---------------------------------------------------------------------------
// Kernel 2 (v11): L2-dedup + tile stagger. UNCHANGED this round (one
// variable per round; v11 just landed 48 -> ~35 us confirmed by totals).
// Round-13 theory (from v10 ablation): all phase ablations ~= full kernel ->
// the wall is the LOADS. They are redundant: Gf/phB voffsets don't depend on
// wave -> 4x intra-block duplication; 64 q-blocks/batch re-read the same
// 80 KB phi/gT in LOCK-STEP tile order -> ~512 MB of L2-line traffic through
// the same hot lines at ~13 TB/s effective = V5's floor.
// v11: (1) G-tile (4 KB) staged ONCE per block via asm loads + XOR-swizzled
// ds_write; PV reads frags via swizzled ds_read_b128. One __syncthreads per
// tile = the cross-wave hand-off. (2) Stagger tile order st=(t+blk&15)&15 —
// legal: non-online softmax, tile order is permutation-invariant.
// vmcnt ledger: 5 loads/body; vmcnt(4) before ds_write, vmcnt(5) before QK,
// body-15 waits 0. LDS: P 18432 + stage 8192 = 26624 B.
// ---------------------------------------------------------------------------
__global__ __launch_bounds__(256) __attribute__((amdgpu_waves_per_eu(4, 4)))
void k_attn(
    const float* __restrict__ x, const float* __restrict__ Wo,
    const float* __restrict__ gamma_p, const unsigned short* __restrict__ ws,
    float* __restrict__ out)
{
    __shared__ __align__(16) unsigned char smem[26624];

    const int tid  = threadIdx.x;
    const int wave = __builtin_amdgcn_readfirstlane(tid >> 6);
    const int lane = tid & 63;
    const int quad = lane >> 4, lr = lane & 15;
    const int blk  = blockIdx.x;
    const int b    = blk >> 6;
    const int q0   = (blk & 63) * 64;
    const int stoff = blk & 15;               // tile stagger (block-uniform)

    const unsigned short* th = ws + (size_t)b * HWs * 8;
    const unsigned short* ph = ws + PHI_OFF + (size_t)b * NPS * 8;
    const unsigned short* gp = ws + GT_OFF + (size_t)b * 32 * NPS;
    unsigned short* Pw  = (unsigned short*)smem + wave * 2304;     // 2 bufs x [16 q][72 s]
    unsigned short* stg = (unsigned short*)(smem + 18432);         // 2 bufs x [32 ch][64 s]

    // G staging map: thread -> one 16B chunk (ch = tid>>3, part = tid&7),
    // XOR-swizzled column so frag reads spread across banks.
    const int sch   = tid >> 3;
    const int spart = tid & 7;
    const int swz   = spart ^ (sch & 7);
    const int voff_gc = sch * (NPS * 2) + spart * 16;   // byte voffset into gT slab

    const s16x8 zf = {0, 0, 0, 0, 0, 0, 0, 0};
    const f32x4 zc = {0.f, 0.f, 0.f, 0.f};

    // theta A-fragment: A[m=q=lr][k=quad*8+j], real k<8 in quad 0
    const s16x8 thA = (quad == 0) ? LD8G(th + (size_t)(q0 + wave * 16 + lr) * 8) : zf;

    f32x4 O[2];
    f32x4 l4;
#pragma unroll
    for (int r = 0; r < 4; ++r) { O[0][r] = 0.f; O[1][r] = 0.f; l4[r] = 0.f; }

    // per-lane phi byte voffsets (loop-invariant)
    const int voff_ph0 = (0 * 16 + lr) * 16;
    const int voff_ph1 = (1 * 16 + lr) * 16;
    const int voff_ph2 = (2 * 16 + lr) * 16;
    const int voff_ph3 = (3 * 16 + lr) * 16;

    s16x8 phB_e[4], phB_o[4];
    s16x8 greg_e, greg_o;

#define GL4(dst, off, base)                                                   \
    asm volatile("global_load_dwordx4 %0, %1, %2"                             \
                 : "=v"(dst) : "v"(off), "s"(base) : "memory")

#define LOADPH_A(dst, baseT)                                                  \
    GL4(dst[0], voff_ph0, baseT); GL4(dst[1], voff_ph1, baseT);               \
    GL4(dst[2], voff_ph2, baseT); GL4(dst[3], voff_ph3, baseT);

#define WAITVM(n) asm volatile("s_waitcnt vmcnt(" #n ")" ::: "memory")

#define QK(Sv, phB)                                                           \
    _Pragma("unroll")                                                         \
    for (int ss = 0; ss < 4; ++ss)                                            \
        Sv[ss] = __builtin_amdgcn_mfma_f32_16x16x32_bf16(thA, phB[ss], zc, 0, 0, 0);

#define EXPST(Sv, wbuf)                                                       \
    _Pragma("unroll")                                                         \
    for (int ss = 0; ss < 4; ++ss)                                            \
        _Pragma("unroll")                                                     \
        for (int r = 0; r < 4; ++r) {                                         \
            const float p = exp2f(Sv[ss][r]);                                 \
            l4[r] += p;                                                       \
            Pw[(wbuf) + (quad * 4 + r) * 72 + ss * 16 + lr] =                 \
                (unsigned short)(__float_as_uint(p) >> 16);                   \
        }

#define BODY(phCUR, phNXT, gCUR, gNXT, curT, LAST)                            \
    {                                                                         \
        WAITVM(4);   /* retire G chunk of st(curT) (oldest of 5) */           \
        __syncthreads();                                                      \
        *(s16x8*)(stg + ((curT) & 1) * 2048 + sch * 64 + swz * 8) = gCUR;     \
        if (!(LAST)) {                                                        \
            const int stn = ((curT) + 1 + stoff) & 15;                        \
            GL4(gNXT, voff_gc, gp + (size_t)stn * 64);                        \
            LOADPH_A(phNXT, ph + (size_t)stn * 512);                          \
        }                                                                     \
        const int pb = ((curT) - 1) & 1;                                      \
        const s16x8 Pf0 = *(const s16x8*)(Pw + pb * 1152 + lr * 72 + quad * 8);      \
        const s16x8 Pf1 = *(const s16x8*)(Pw + pb * 1152 + lr * 72 + 32 + quad * 8); \
        s16x8 Gf[2][2];                                                       \
        _Pragma("unroll")                                                     \
        for (int kc = 0; kc < 2; ++kc)                                        \
            _Pragma("unroll")                                                 \
            for (int cs = 0; cs < 2; ++cs)                                    \
                Gf[kc][cs] = *(const s16x8*)(stg + pb * 2048 +                \
                    (cs * 16 + lr) * 64 + ((kc * 4 + quad) ^ (lr & 7)) * 8);  \
        if (LAST) { WAITVM(0); } else { WAITVM(5); }  /* phi(st(curT)) */     \
        SB();                                                                 \
        f32x4 S[4];                                                           \
        QK(S, phCUR);                                                         \
        _Pragma("unroll")                                                     \
        for (int cs = 0; cs < 2; ++cs)                                        \
            O[cs] = __builtin_amdgcn_mfma_f32_16x16x32_bf16(Pf0, Gf[0][cs], O[cs], 0, 0, 0); \
        _Pragma("unroll")                                                     \
        for (int cs = 0; cs < 2; ++cs)                                        \
            O[cs] = __builtin_amdgcn_mfma_f32_16x16x32_bf16(Pf1, Gf[1][cs], O[cs], 0, 0, 0); \
        EXPST(S, ((curT) & 1) * 1152);                                        \
    }

    // ---- prologue: tile st(0) ----
    {
        const int st0 = stoff;
        const int st1 = (stoff + 1) & 15;
        GL4(greg_e, voff_gc, gp + (size_t)st0 * 64);
        LOADPH_A(phB_e, ph + (size_t)st0 * 512);
        WAITVM(4);                              // retire G(st0)
        *(s16x8*)(stg + 0 * 2048 + sch * 64 + swz * 8) = greg_e;
        GL4(greg_o, voff_gc, gp + (size_t)st1 * 64);
        LOADPH_A(phB_o, ph + (size_t)st1 * 512);
        WAITVM(5);                              // retire phi(st0)
        SB();
        f32x4 S[4];
        QK(S, phB_e);
        EXPST(S, 0);
    }

    // ---- steady state: t = 1..14 in ping-pong pairs ----
    for (int t = 1; t < 15; t += 2) {
        BODY(phB_o, phB_e, greg_o, greg_e, t,     0);
        BODY(phB_e, phB_o, greg_e, greg_o, t + 1, 0);
    }
    // ---- t = 15 (no next prefetch) ----
    BODY(phB_o, phB_e, greg_o, greg_e, 15, 1);

    // ---- drain: PV for tile st(15) (P in buf1, G in stage[1]) ----
    {
        __syncthreads();                        // stage[1] written by all
        const s16x8 Pf0 = *(const s16x8*)(Pw + 1152 + lr * 72 + quad * 8);
        const s16x8 Pf1 = *(const s16x8*)(Pw + 1152 + lr * 72 + 32 + quad * 8);
        s16x8 Gf[2][2];
#pragma unroll
        for (int kc = 0; kc < 2; ++kc)
#pragma unroll
            for (int cs = 0; cs < 2; ++cs)
                Gf[kc][cs] = *(const s16x8*)(stg + 2048 +
                    (cs * 16 + lr) * 64 + ((kc * 4 + quad) ^ (lr & 7)) * 8);
#pragma unroll
        for (int cs = 0; cs < 2; ++cs)
            O[cs] = __builtin_amdgcn_mfma_f32_16x16x32_bf16(Pf0, Gf[0][cs], O[cs], 0, 0, 0);
#pragma unroll
        for (int cs = 0; cs < 2; ++cs)
            O[cs] = __builtin_amdgcn_mfma_f32_16x16x32_bf16(Pf1, Gf[1][cs], O[cs], 0, 0, 0);
    }

    // l: butterfly-sum over the 16-lane s-groups
#pragma unroll
    for (int r = 0; r < 4; ++r) {
        float v = l4[r];
        v += __shfl_xor(v, 1);
        v += __shfl_xor(v, 2);
        v += __shfl_xor(v, 4);
        v += __shfl_xor(v, 8);
        l4[r] = 1.f / v;
    }

    __syncthreads();                          // all waves done with Pw/stage
    float* otile = (float*)smem;              // [32 c][68 q-stride]
#pragma unroll
    for (int cs = 0; cs < 2; ++cs) {
        f32x4 v;
#pragma unroll
        for (int r = 0; r < 4; ++r) v[r] = O[cs][r] * l4[r];
        *(f32x4*)(otile + (cs * 16 + lr) * 68 + wave * 16 + quad * 4) = v;
    }
    __syncthreads();

    // Wo epilogue + residual: thread = (q = tid&63, oc quarter = tid>>6)
    const int qq = tid & 63;
    const int quarter = __builtin_amdgcn_readfirstlane(tid >> 6);
    float ov[32];
#pragma unroll
    for (int c = 0; c < 32; ++c) ov[c] = otile[c * 68 + qq];
    const float gam = gamma_p[0];
#pragma unroll
    for (int j = 0; j < 16; ++j) {
        const float* wrow = Wo + (size_t)(quarter * 16 + j) * 32;  // contiguous
        float a = 0.f;
#pragma unroll
        for (int c = 0; c < 32; ++c) a += wrow[c] * ov[c];         // s_load
        const size_t ad = ((size_t)b * NC + quarter * 16 + j) * HWs + q0 + qq;
        out[ad] = gam * a + x[ad];
    }
}

extern "C" void kernel_launch(void* const* d_in, const int* in_sizes, int n_in,
                              void* d_out, int out_size, void* d_ws, size_t ws_size,
                              hipStream_t stream) {
    const float* x     = (const float*)d_in[0];
    const float* Wt    = (const float*)d_in[1];
    const float* Wp    = (const float*)d_in[2];
    const float* Wg    = (const float*)d_in[3];
    const float* Wo    = (const float*)d_in[4];
    const float* gamma = (const float*)d_in[5];
    float* out = (float*)d_out;
    unsigned short* ws = (unsigned short*)d_ws;

    k_proj<<<2048, 256, 0, stream>>>(x, Wt, Wp, Wg, ws);
    k_attn<<<1024, 256, 0, stream>>>(x, Wo, gamma, ws, out);
}